// Round 22
// baseline (1787.530 us; speedup 1.0000x reference)
//
#include <hip/hip_runtime.h>
#include <hip/hip_bf16.h>
#include <cmath>

// GMM E-step: N=131072, K=64, D=256.
// Round 22: r21 (XCD-aligned k-partitioning: grid 8192, block = rows
// (bid>>3) x components [(bid&7)*8,+8), L2-resident 1MB Pb slice per
// XCD) with the dot-correction DUPLICATION BUG fixed: kdim chunks are
// partitioned across wc (each wave computes a partial G over kdims
// [wc*64, wc*64+64)); the 4 wc-partials ds_add to the full -2G exactly
// once. Sync structure identical to validated r16.

typedef unsigned short ushort_t;
typedef __attribute__((ext_vector_type(4))) float f32x4;
typedef __attribute__((ext_vector_type(8))) short bf16x8;

constexpr int N_ = 131072;
constexpr int K_ = 64;
constexpr int D_ = 256;
constexpr int BM = 128;                 // rows per block
constexpr int NBLK = (N_ / BM) * 8;     // 8192 blocks (rows x k-ranges)

// ---------- helpers ----------
__device__ __forceinline__ ushort_t f2bf(float v) {
  unsigned u = __float_as_uint(v);
  u += 0x7FFFu + ((u >> 16) & 1u);  // RNE
  return (ushort_t)(u >> 16);
}

__device__ __forceinline__ void gld16(const ushort_t* g, ushort_t* l) {
  __builtin_amdgcn_global_load_lds(
      (const __attribute__((address_space(1))) unsigned int*)g,
      (__attribute__((address_space(3))) unsigned int*)l, 16, 0, 0);
}

// 16-lane (lc-group) sum, VALU-only DPP tree.
__device__ __forceinline__ float dpp_red16(float v) {
  int x = __float_as_int(v);
  v += __int_as_float(__builtin_amdgcn_update_dpp(0, x, 0xB1, 0xF, 0xF, true));
  x = __float_as_int(v);
  v += __int_as_float(__builtin_amdgcn_update_dpp(0, x, 0x4E, 0xF, 0xF, true));
  x = __float_as_int(v);
  v += __int_as_float(__builtin_amdgcn_update_dpp(0, x, 0x141, 0xF, 0xF, true));
  x = __float_as_int(v);
  v += __int_as_float(__builtin_amdgcn_update_dpp(0, x, 0x140, 0xF, 0xF, true));
  return v;
}

// ---------- prep: X fp32 -> bf16 A-fragment image ----------
// e = ((T*8 + mm)*8 + kc)*512 + lane*8 + j  holds
//   bf16( X[T*128 + mm*16 + (lane&15)][kc*32 + (lane>>4)*8 + j] )
__global__ void prep_x(const float* __restrict__ X, ushort_t* __restrict__ Xb) {
  for (int e = blockIdx.x * blockDim.x + threadIdx.x; e < N_ * D_;
       e += gridDim.x * blockDim.x) {
    int j = e & 7;
    int lane = (e >> 3) & 63;
    int kc = (e >> 9) & 7;
    int mm = (e >> 12) & 7;
    int T = e >> 15;
    int row = T * 128 + mm * 16 + (lane & 15);
    int col = kc * 32 + (lane >> 4) * 8 + j;
    Xb[e] = f2bf(X[(size_t)row * D_ + col]);
  }
}

// ---------- prep: P fp32 -> bf16 B substep image (BK=32) ----------
// e = (g*16 + wc*4 + n)*512 + lane*8 + j,  g = k*8 + s,  holds
//   bf16( P[k][s*32 + (lane>>4)*8 + j][wc*64 + n*16 + (lane&15)] )
__global__ void prep_p(const float* __restrict__ P, ushort_t* __restrict__ Pb) {
  for (int e = blockIdx.x * blockDim.x + threadIdx.x; e < K_ * D_ * D_;
       e += gridDim.x * blockDim.x) {
    int j = e & 7;
    int lane = (e >> 3) & 63;
    int n = (e >> 9) & 3;
    int wc = (e >> 11) & 3;
    int g = e >> 13;
    int k = g >> 3, s = g & 7;
    int row_p = s * 32 + (lane >> 4) * 8 + j;
    int col_p = wc * 64 + n * 16 + (lane & 15);
    Pb[e] = f2bf(P[((size_t)k * D_ + row_p) * D_ + col_p]);
  }
}

// ---------- prep: t, ||t||^2, C2[k], u_k -> range-Ub image ----------
// Ub image (pre-zeroed): e = ((k>>3)*8 + chunk)*512 + lane*8 + j holds
//   bf16( u[col = k&7 = lane&15][kdim = chunk*32 + (lane>>4)*8 + j] )
// cols 8..15 of each fragment stay zero.
__global__ void prep_t(const float* __restrict__ P, const float* __restrict__ mu,
                       const float* __restrict__ w, ushort_t* __restrict__ Ub,
                       float* __restrict__ C2) {
  int k = blockIdx.x, j = threadIdx.x;
  const float* Pk = P + (size_t)k * D_ * D_;
  const float* muk = mu + (size_t)k * D_;
  __shared__ float tl[D_];
  __shared__ float red[D_];
  float acc = 0.f;
  for (int i = 0; i < D_; ++i) acc += muk[i] * Pk[(size_t)i * D_ + j];
  tl[j] = acc;
  red[j] = acc * acc;  // for ||t||^2
  __syncthreads();
  for (int s = 128; s > 0; s >>= 1) {
    if (j < s) red[j] += red[j + s];
    __syncthreads();
  }
  float tn = red[0];
  __syncthreads();
  red[j] = logf(Pk[(size_t)j * D_ + j]);
  __syncthreads();
  for (int s = 128; s > 0; s >>= 1) {
    if (j < s) red[j] += red[j + s];
    __syncthreads();
  }
  if (j == 0)
    C2[k] = red[0] + logf(w[k]) - 0.5f * (float)D_ * logf(2.0f * (float)M_PI) -
            0.5f * tn;
  // phase 2: u_i = sum_j Pk[i][j] * t[j]; write into range image
  float u = 0.f;
  for (int jj = 0; jj < D_; ++jj) u += Pk[(size_t)j * D_ + jj] * tl[jj];
  int lane = (k & 7) + 16 * ((j >> 3) & 3);
  int e = ((k >> 3) * 8 + (j >> 5)) * 512 + lane * 8 + (j & 7);
  Ub[e] = f2bf(u);
}

// ---------- main ----------
__global__ __launch_bounds__(512, 2) void gmm_main(
    const ushort_t* __restrict__ Xb, const ushort_t* __restrict__ Pb,
    const ushort_t* __restrict__ Ub,
    float* __restrict__ wlp /* [N][K], raw-adjusted sq written */) {
  __shared__ __align__(16) ushort_t Bl[8 * 8192];  // 128 KiB, ring-8
  __shared__ float sqf[BM * 8];                    // 4 KiB accumulator

  const int tid = threadIdx.x;
  const int bid = blockIdx.x;
  const int T = bid >> 3;        // row tile
  const int rng = bid & 7;       // component range (XCD-aligned)
  const int k0 = rng * 8;

  const int lane = tid & 63, wid = tid >> 6;
  const int wr = wid >> 2, wc = wid & 3;  // wave tile: 64 rows x 64 cols
  const int lc = lane & 15, lg = lane >> 4;

  // zero sq accumulator (1024 floats, 2/thread)
  sqf[tid] = 0.f;
  sqf[tid + 512] = 0.f;

  // ---- A fragments in registers: 32 x bf16x8 (AGPR-allocated) ----
  const ushort_t* Ag = Xb + (size_t)T * 32768;
  bf16x8 Areg[32];  // index m*8 + s (s = 32-wide k-chunk)
#pragma unroll
  for (int m = 0; m < 4; ++m)
#pragma unroll
    for (int c = 0; c < 8; ++c)
      Areg[m * 8 + c] =
          *(const bf16x8*)&Ag[(((wr * 4 + m) * 8 + c) * 512) + lane * 8];

  // ---- prologue: stage local substeps 0..3 into bufs 0..3, drain ----
  const ushort_t* Pbase = Pb + (size_t)k0 * 65536;  // this range's slice
#pragma unroll
  for (int g0 = 0; g0 < 4; ++g0)
#pragma unroll
    for (int it = 0; it < 2; ++it)
      gld16(Pbase + (size_t)g0 * 8192 + (it * 512 + tid) * 8,
            &Bl[g0 * 8192 + (it * 512 + tid) * 8]);
  asm volatile("s_waitcnt vmcnt(0) lgkmcnt(0)" ::: "memory");
  __builtin_amdgcn_s_barrier();

#pragma unroll 1
  for (int kk = 0; kk < 8; ++kk) {
    f32x4 acc[4][4];
#pragma unroll
    for (int m = 0; m < 4; ++m)
#pragma unroll
      for (int n = 0; n < 4; ++n) acc[m][n] = (f32x4){0.f, 0.f, 0.f, 0.f};

#pragma unroll
    for (int w = 0; w < 4; ++w) {
      const int s = 2 * w;
      // stage local substeps L+4, L+5 into bufs (s+4)&7, (s+5)&7
      int L4 = kk * 8 + s + 4;
      if (L4 > 63) L4 = 63;  // clamped writes land in bufs never read again
      int L5 = kk * 8 + s + 5;
      if (L5 > 63) L5 = 63;
      {
        const ushort_t* p4 = Pbase + (size_t)L4 * 8192;
        ushort_t* d4 = &Bl[((s + 4) & 7) * 8192];
#pragma unroll
        for (int it = 0; it < 2; ++it)
          gld16(p4 + (it * 512 + tid) * 8, d4 + (it * 512 + tid) * 8);
      }
      {
        const ushort_t* p5 = Pbase + (size_t)L5 * 8192;
        ushort_t* d5 = &Bl[((s + 5) & 7) * 8192];
#pragma unroll
        for (int it = 0; it < 2; ++it)
          gld16(p5 + (it * 512 + tid) * 8, d5 + (it * 512 + tid) * 8);
      }
      // counted: retire this window's data (2 windows old); 8 newer fly
      asm volatile("s_waitcnt vmcnt(8)" ::: "memory");
      __builtin_amdgcn_s_barrier();

      // compute both substeps (32 MFMA window)
#pragma unroll
      for (int h = 0; h < 2; ++h) {
        const int ss = s + h;
        bf16x8 bb[4];
#pragma unroll
        for (int n = 0; n < 4; ++n)
          bb[n] =
              *(const bf16x8*)&Bl[ss * 8192 + (wc * 4 + n) * 512 + lane * 8];
#pragma unroll
        for (int m = 0; m < 4; ++m)
#pragma unroll
          for (int n = 0; n < 4; ++n)
            acc[m][n] = __builtin_amdgcn_mfma_f32_16x16x32_bf16(
                Areg[m * 8 + ss], bb[n], acc[m][n], 0, 0, 0);
      }
    }

    // epilogue: RAW ||Z||^2, DPP reduce, ds_add (no barrier)
#pragma unroll
    for (int m = 0; m < 4; ++m)
#pragma unroll
      for (int r = 0; r < 4; ++r) {
        float a0 = acc[m][0][r], a1 = acc[m][1][r];
        float a2 = acc[m][2][r], a3 = acc[m][3][r];
        float sfl = dpp_red16(a0 * a0 + a1 * a1 + a2 * a2 + a3 * a3);
        if (lc == 0) {
          int row = wr * 64 + m * 16 + lg * 4 + r;
          atomicAdd(&sqf[row * 8 + kk], sfl);
        }
      }
  }

  // ---- dot-correction: G = X.u_range^T, kdim chunks SPLIT ACROSS wc.
  // Wave wc computes the partial over kdims [wc*64, wc*64+64) (chunks
  // wc*2, wc*2+1); the 4 wc-partials ds_add to the full -2G once each.
  bf16x8 Uf[2];
#pragma unroll
  for (int c2 = 0; c2 < 2; ++c2)
    Uf[c2] = *(const bf16x8*)&Ub[((size_t)rng * 8 + wc * 2 + c2) * 512 +
                                 lane * 8];
  f32x4 accd[4];
#pragma unroll
  for (int m = 0; m < 4; ++m) accd[m] = (f32x4){0.f, 0.f, 0.f, 0.f};
#pragma unroll
  for (int c2 = 0; c2 < 2; ++c2)
#pragma unroll
    for (int m = 0; m < 4; ++m)
      accd[m] = __builtin_amdgcn_mfma_f32_16x16x32_bf16(
          Areg[m * 8 + wc * 2 + c2], Uf[c2], accd[m], 0, 0, 0);
#pragma unroll
  for (int m = 0; m < 4; ++m)
#pragma unroll
    for (int r = 0; r < 4; ++r) {
      if (lc < 8) {
        int row = wr * 64 + m * 16 + lg * 4 + r;
        atomicAdd(&sqf[row * 8 + lc], -2.0f * accd[m][r]);
      }
    }

  __syncthreads();  // all ds_adds visible

  // flush: sqf [128][8] -> wlp rows' 8-wide k-slice (exclusive to block)
  if (tid < 256) {
    int row = tid >> 1, half = tid & 1;
    float* dst = wlp + ((size_t)(T * 128 + row)) * 64 + k0 + half * 4;
    *(f32x4*)dst = *(const f32x4*)&sqf[row * 8 + half * 4];
  }
}

// ---------- LSE over k: v = -0.5*sq' + C2, logsumexp, log_resp ---------
__global__ void lse_k(float* __restrict__ out, const float* __restrict__ C2,
                      float* __restrict__ partial) {
  __shared__ float C2l[K_];
  if (threadIdx.x < K_) C2l[threadIdx.x] = C2[threadIdx.x];
  __syncthreads();
  const int row = blockIdx.x * 256 + threadIdx.x;
  float* w = out + 1 + (size_t)row * K_;
  float v[K_];
  float mx = -1e30f;
#pragma unroll
  for (int j = 0; j < K_; ++j) {
    v[j] = -0.5f * w[j] + C2l[j];
    mx = fmaxf(mx, v[j]);
  }
  float ssum = 0.f;
#pragma unroll
  for (int j = 0; j < K_; ++j) ssum += expf(v[j] - mx);
  float l = mx + logf(ssum);
#pragma unroll
  for (int j = 0; j < K_; ++j) w[j] = v[j] - l;
  __shared__ float red[256];
  red[threadIdx.x] = l;
  __syncthreads();
  for (int s = 128; s > 0; s >>= 1) {
    if (threadIdx.x < s) red[threadIdx.x] += red[threadIdx.x + s];
    __syncthreads();
  }
  if (threadIdx.x == 0) partial[blockIdx.x] = red[0];
}

__global__ void final_red(const float* __restrict__ partial,
                          float* __restrict__ out) {
  __shared__ float red[512];
  red[threadIdx.x] = partial[threadIdx.x];
  __syncthreads();
  for (int s = 256; s > 0; s >>= 1) {
    if (threadIdx.x < s) red[threadIdx.x] += red[threadIdx.x + s];
    __syncthreads();
  }
  if (threadIdx.x == 0) out[0] = red[0] * (1.0f / (float)N_);
}

extern "C" void kernel_launch(void* const* d_in, const int* in_sizes, int n_in,
                              void* d_out, int out_size, void* d_ws,
                              size_t ws_size, hipStream_t stream) {
  const float* X = (const float*)d_in[0];
  const float* w = (const float*)d_in[1];
  const float* mu = (const float*)d_in[2];
  const float* P = (const float*)d_in[3];
  float* out = (float*)d_out;
  char* ws = (char*)d_ws;

  // ws layout (bytes) — total 75,565,312
  ushort_t* Xb = (ushort_t*)ws;                 // 67,108,864
  ushort_t* Pb = (ushort_t*)(ws + 67108864);    // 8,388,608
  ushort_t* Ub = (ushort_t*)(ws + 75497472);    // 65,536 (range-Ub image)
  float* C2 = (float*)(ws + 75563008);          // 256
  float* partial = (float*)(ws + 75563264);     // 2,048

  hipMemsetAsync(Ub, 0, 65536, stream);  // zero cols 8..15 of fragments
  prep_x<<<2048, 256, 0, stream>>>(X, Xb);
  prep_p<<<2048, 256, 0, stream>>>(P, Pb);
  prep_t<<<K_, 256, 0, stream>>>(P, mu, w, Ub, C2);
  gmm_main<<<NBLK, 512, 0, stream>>>(Xb, Pb, Ub, out + 1);
  lse_k<<<N_ / 256, 256, 0, stream>>>(out, C2, partial);
  final_red<<<1, 512, 0, stream>>>(partial, out);
}

// Round 23
// 999.368 us; speedup vs baseline: 1.7887x; 1.7887x over previous
//
#include <hip/hip_runtime.h>
#include <hip/hip_bf16.h>
#include <cmath>

// GMM E-step: N=131072, K=64, D=256.
// Round 23: REVERT to round-16 exactly — the validated best (1012us,
// MfmaUtil 46.8%, 0 bank conflicts). Ring-8 (static s&7 indexing),
// barrier per 2 substeps, stage-4-ahead with counted vmcnt(8) (never
// drained), raw-||Z||^2 epilogue (VALU-DPP reduce, ds_add combine),
// MFMA dot-correction phase, C2 fold in lse. r17-r22 variants all
// regressed or failed; this is the best-known state.

typedef unsigned short ushort_t;
typedef __attribute__((ext_vector_type(4))) float f32x4;
typedef __attribute__((ext_vector_type(8))) short bf16x8;

constexpr int N_ = 131072;
constexpr int K_ = 64;
constexpr int D_ = 256;
constexpr int BM = 128;                 // rows per block
constexpr int NBLK = N_ / BM;           // 1024 blocks

// ---------- helpers ----------
__device__ __forceinline__ ushort_t f2bf(float v) {
  unsigned u = __float_as_uint(v);
  u += 0x7FFFu + ((u >> 16) & 1u);  // RNE
  return (ushort_t)(u >> 16);
}

__device__ __forceinline__ void gld16(const ushort_t* g, ushort_t* l) {
  __builtin_amdgcn_global_load_lds(
      (const __attribute__((address_space(1))) unsigned int*)g,
      (__attribute__((address_space(3))) unsigned int*)l, 16, 0, 0);
}

// 16-lane (lc-group) sum, VALU-only DPP tree.
__device__ __forceinline__ float dpp_red16(float v) {
  int x = __float_as_int(v);
  v += __int_as_float(__builtin_amdgcn_update_dpp(0, x, 0xB1, 0xF, 0xF, true));
  x = __float_as_int(v);
  v += __int_as_float(__builtin_amdgcn_update_dpp(0, x, 0x4E, 0xF, 0xF, true));
  x = __float_as_int(v);
  v += __int_as_float(__builtin_amdgcn_update_dpp(0, x, 0x141, 0xF, 0xF, true));
  x = __float_as_int(v);
  v += __int_as_float(__builtin_amdgcn_update_dpp(0, x, 0x140, 0xF, 0xF, true));
  return v;
}

// ---------- prep: X fp32 -> bf16 A-fragment image ----------
// e = ((T*8 + mm)*8 + kc)*512 + lane*8 + j  holds
//   bf16( X[T*128 + mm*16 + (lane&15)][kc*32 + (lane>>4)*8 + j] )
__global__ void prep_x(const float* __restrict__ X, ushort_t* __restrict__ Xb) {
  for (int e = blockIdx.x * blockDim.x + threadIdx.x; e < N_ * D_;
       e += gridDim.x * blockDim.x) {
    int j = e & 7;
    int lane = (e >> 3) & 63;
    int kc = (e >> 9) & 7;
    int mm = (e >> 12) & 7;
    int T = e >> 15;
    int row = T * 128 + mm * 16 + (lane & 15);
    int col = kc * 32 + (lane >> 4) * 8 + j;
    Xb[e] = f2bf(X[(size_t)row * D_ + col]);
  }
}

// ---------- prep: P fp32 -> bf16 B substep image (BK=32) ----------
// e = (g*16 + wc*4 + n)*512 + lane*8 + j,  g = k*8 + s,  holds
//   bf16( P[k][s*32 + (lane>>4)*8 + j][wc*64 + n*16 + (lane&15)] )
__global__ void prep_p(const float* __restrict__ P, ushort_t* __restrict__ Pb) {
  for (int e = blockIdx.x * blockDim.x + threadIdx.x; e < K_ * D_ * D_;
       e += gridDim.x * blockDim.x) {
    int j = e & 7;
    int lane = (e >> 3) & 63;
    int n = (e >> 9) & 3;
    int wc = (e >> 11) & 3;
    int g = e >> 13;
    int k = g >> 3, s = g & 7;
    int row_p = s * 32 + (lane >> 4) * 8 + j;
    int col_p = wc * 64 + n * 16 + (lane & 15);
    Pb[e] = f2bf(P[((size_t)k * D_ + row_p) * D_ + col_p]);
  }
}

// ---------- prep: t, ||t||^2, C2[k], u_k = P_k t_k -> Ub image ---------
// Ub image: e = (chunk*4 + k>>4)*512 + lane*8 + j holds
//   bf16( u[kcomp = (k>>4)*16 + (lane&15)][kdim = chunk*32 + (lane>>4)*8+j] )
__global__ void prep_t(const float* __restrict__ P, const float* __restrict__ mu,
                       const float* __restrict__ w, ushort_t* __restrict__ Ub,
                       float* __restrict__ C2) {
  int k = blockIdx.x, j = threadIdx.x;
  const float* Pk = P + (size_t)k * D_ * D_;
  const float* muk = mu + (size_t)k * D_;
  __shared__ float tl[D_];
  __shared__ float red[D_];
  float acc = 0.f;
  for (int i = 0; i < D_; ++i) acc += muk[i] * Pk[(size_t)i * D_ + j];
  tl[j] = acc;
  red[j] = acc * acc;  // for ||t||^2
  __syncthreads();
  for (int s = 128; s > 0; s >>= 1) {
    if (j < s) red[j] += red[j + s];
    __syncthreads();
  }
  float tn = red[0];
  __syncthreads();
  red[j] = logf(Pk[(size_t)j * D_ + j]);
  __syncthreads();
  for (int s = 128; s > 0; s >>= 1) {
    if (j < s) red[j] += red[j + s];
    __syncthreads();
  }
  if (j == 0)
    C2[k] = red[0] + logf(w[k]) - 0.5f * (float)D_ * logf(2.0f * (float)M_PI) -
            0.5f * tn;
  // phase 2: u_i = sum_j Pk[i][j] * t[j]
  float u = 0.f;
  for (int jj = 0; jj < D_; ++jj) u += Pk[(size_t)j * D_ + jj] * tl[jj];
  int e = ((j >> 5) * 4 + (k >> 4)) * 512 +
          (((j >> 3) & 3) * 16 + (k & 15)) * 8 + (j & 7);
  Ub[e] = f2bf(u);
}

// ---------- main ----------
__global__ __launch_bounds__(512, 2) void gmm_main(
    const ushort_t* __restrict__ Xb, const ushort_t* __restrict__ Pb,
    const ushort_t* __restrict__ Ub,
    float* __restrict__ wlp /* [N][K], raw-adjusted sq written */) {
  __shared__ __align__(16) ushort_t Bl[8 * 8192];  // 128 KiB, ring-8
  __shared__ float sqf[BM * K_];                   // 32 KiB accumulator

  const int tid = threadIdx.x;
  const int T = blockIdx.x;
  const int lane = tid & 63, wid = tid >> 6;
  const int wr = wid >> 2, wc = wid & 3;  // wave tile: 64 rows x 64 cols
  const int lc = lane & 15, lg = lane >> 4;

  // zero sq accumulator (8192 floats, 16/thread)
#pragma unroll
  for (int i = 0; i < 16; ++i) sqf[tid + i * 512] = 0.f;

  // ---- A fragments in registers: 32 x bf16x8 (AGPR-allocated) ----
  const ushort_t* Ag = Xb + (size_t)T * 32768;
  bf16x8 Areg[32];  // index m*8 + s (s = 32-wide k-chunk)
#pragma unroll
  for (int m = 0; m < 4; ++m)
#pragma unroll
    for (int c = 0; c < 8; ++c)
      Areg[m * 8 + c] =
          *(const bf16x8*)&Ag[(((wr * 4 + m) * 8 + c) * 512) + lane * 8];

  // ---- prologue: stage substeps 0..3 into bufs 0..3 ----
#pragma unroll
  for (int g0 = 0; g0 < 4; ++g0)
#pragma unroll
    for (int it = 0; it < 2; ++it)
      gld16(Pb + (size_t)g0 * 8192 + (it * 512 + tid) * 8,
            &Bl[g0 * 8192 + (it * 512 + tid) * 8]);
  asm volatile("s_waitcnt vmcnt(0) lgkmcnt(0)" ::: "memory");
  __builtin_amdgcn_s_barrier();

#pragma unroll 1
  for (int k = 0; k < K_; ++k) {
    f32x4 acc[4][4];
#pragma unroll
    for (int m = 0; m < 4; ++m)
#pragma unroll
      for (int n = 0; n < 4; ++n) acc[m][n] = (f32x4){0.f, 0.f, 0.f, 0.f};

#pragma unroll
    for (int s = 0; s < 8; s += 2) {
      // stage substeps g+4, g+5 into bufs (s+4)&7, (s+5)&7 (static!)
      int g4 = k * 8 + s + 4;
      if (g4 > 511) g4 = 511;  // clamped writes land in bufs never read again
      int g5 = k * 8 + s + 5;
      if (g5 > 511) g5 = 511;
      {
        const ushort_t* p4 = Pb + (size_t)g4 * 8192;
        ushort_t* d4 = &Bl[((s + 4) & 7) * 8192];
#pragma unroll
        for (int it = 0; it < 2; ++it)
          gld16(p4 + (it * 512 + tid) * 8, d4 + (it * 512 + tid) * 8);
      }
      {
        const ushort_t* p5 = Pb + (size_t)g5 * 8192;
        ushort_t* d5 = &Bl[((s + 5) & 7) * 8192];
#pragma unroll
        for (int it = 0; it < 2; ++it)
          gld16(p5 + (it * 512 + tid) * 8, d5 + (it * 512 + tid) * 8);
      }
      // counted: retire this interval's data (oldest 4); 8 newer fly on
      asm volatile("s_waitcnt vmcnt(8)" ::: "memory");
      __builtin_amdgcn_s_barrier();

      // compute both substeps (32 MFMA window, ds_reads free to overlap)
#pragma unroll
      for (int h = 0; h < 2; ++h) {
        const int ss = s + h;
        bf16x8 bb[4];
#pragma unroll
        for (int n = 0; n < 4; ++n)
          bb[n] =
              *(const bf16x8*)&Bl[ss * 8192 + (wc * 4 + n) * 512 + lane * 8];
#pragma unroll
        for (int m = 0; m < 4; ++m)
#pragma unroll
          for (int n = 0; n < 4; ++n)
            acc[m][n] = __builtin_amdgcn_mfma_f32_16x16x32_bf16(
                Areg[m * 8 + ss], bb[n], acc[m][n], 0, 0, 0);
      }
    }

    // epilogue: RAW ||Z||^2 (no t), DPP reduce, ds_add (no barrier)
#pragma unroll
    for (int m = 0; m < 4; ++m)
#pragma unroll
      for (int r = 0; r < 4; ++r) {
        float a0 = acc[m][0][r], a1 = acc[m][1][r];
        float a2 = acc[m][2][r], a3 = acc[m][3][r];
        float sfl = dpp_red16(a0 * a0 + a1 * a1 + a2 * a2 + a3 * a3);
        if (lc == 0) {
          int row = wr * 64 + m * 16 + lg * 4 + r;
          atomicAdd(&sqf[row * 64 + k], sfl);
        }
      }
  }

  // ---- dot-correction phase: G = X.u^T (32 MFMA), ds_add(-2G) ----
  bf16x8 Uf[8];
#pragma unroll
  for (int c = 0; c < 8; ++c)
    Uf[c] = *(const bf16x8*)&Ub[(c * 4 + wc) * 512 + lane * 8];
  f32x4 accd[4];
#pragma unroll
  for (int m = 0; m < 4; ++m) accd[m] = (f32x4){0.f, 0.f, 0.f, 0.f};
#pragma unroll
  for (int c = 0; c < 8; ++c)
#pragma unroll
    for (int m = 0; m < 4; ++m)
      accd[m] = __builtin_amdgcn_mfma_f32_16x16x32_bf16(Areg[m * 8 + c], Uf[c],
                                                        accd[m], 0, 0, 0);
#pragma unroll
  for (int m = 0; m < 4; ++m)
#pragma unroll
    for (int r = 0; r < 4; ++r) {
      int row = wr * 64 + m * 16 + lg * 4 + r;
      atomicAdd(&sqf[row * 64 + wc * 16 + lc], -2.0f * accd[m][r]);
    }

  __syncthreads();  // all ds_adds visible

  // flush: sqf [128][64] == wlp tile layout -> straight f32x4 copy
  float* dst = wlp + (size_t)T * BM * K_;
#pragma unroll
  for (int i = 0; i < 4; ++i) {
    int idx4 = tid + i * 512;
    ((f32x4*)dst)[idx4] = *(const f32x4*)&sqf[idx4 * 4];
  }
}

// ---------- LSE over k: v = -0.5*sq' + C2, logsumexp, log_resp ---------
__global__ void lse_k(float* __restrict__ out, const float* __restrict__ C2,
                      float* __restrict__ partial) {
  __shared__ float C2l[K_];
  if (threadIdx.x < K_) C2l[threadIdx.x] = C2[threadIdx.x];
  __syncthreads();
  const int row = blockIdx.x * 256 + threadIdx.x;
  float* w = out + 1 + (size_t)row * K_;
  float v[K_];
  float mx = -1e30f;
#pragma unroll
  for (int j = 0; j < K_; ++j) {
    v[j] = -0.5f * w[j] + C2l[j];
    mx = fmaxf(mx, v[j]);
  }
  float ssum = 0.f;
#pragma unroll
  for (int j = 0; j < K_; ++j) ssum += expf(v[j] - mx);
  float l = mx + logf(ssum);
#pragma unroll
  for (int j = 0; j < K_; ++j) w[j] = v[j] - l;
  __shared__ float red[256];
  red[threadIdx.x] = l;
  __syncthreads();
  for (int s = 128; s > 0; s >>= 1) {
    if (threadIdx.x < s) red[threadIdx.x] += red[threadIdx.x + s];
    __syncthreads();
  }
  if (threadIdx.x == 0) partial[blockIdx.x] = red[0];
}

__global__ void final_red(const float* __restrict__ partial,
                          float* __restrict__ out) {
  __shared__ float red[512];
  red[threadIdx.x] = partial[threadIdx.x];
  __syncthreads();
  for (int s = 256; s > 0; s >>= 1) {
    if (threadIdx.x < s) red[threadIdx.x] += red[threadIdx.x + s];
    __syncthreads();
  }
  if (threadIdx.x == 0) out[0] = red[0] * (1.0f / (float)N_);
}

extern "C" void kernel_launch(void* const* d_in, const int* in_sizes, int n_in,
                              void* d_out, int out_size, void* d_ws,
                              size_t ws_size, hipStream_t stream) {
  const float* X = (const float*)d_in[0];
  const float* w = (const float*)d_in[1];
  const float* mu = (const float*)d_in[2];
  const float* P = (const float*)d_in[3];
  float* out = (float*)d_out;
  char* ws = (char*)d_ws;

  // ws layout (bytes) — total 75,532,544
  ushort_t* Xb = (ushort_t*)ws;                 // 67,108,864
  ushort_t* Pb = (ushort_t*)(ws + 67108864);    // 8,388,608
  ushort_t* Ub = (ushort_t*)(ws + 75497472);    // 32,768 (bf16 u image)
  float* C2 = (float*)(ws + 75530240);          // 256
  float* partial = (float*)(ws + 75530496);     // 2,048

  prep_x<<<2048, 256, 0, stream>>>(X, Xb);
  prep_p<<<2048, 256, 0, stream>>>(P, Pb);
  prep_t<<<K_, 256, 0, stream>>>(P, mu, w, Ub, C2);
  gmm_main<<<NBLK, 512, 0, stream>>>(Xb, Pb, Ub, out + 1);
  lse_k<<<N_ / 256, 256, 0, stream>>>(out, C2, partial);
  final_red<<<1, 512, 0, stream>>>(partial, out);
}